// Round 4
// baseline (1183.113 us; speedup 1.0000x reference)
//
#include <hip/hip_runtime.h>
#include <hip/hip_bf16.h>

#define N_USER 100000
#define N_PHOTO 200000
#define NEDGE 1000000
#define INF 256
#define OUTF 64

typedef unsigned short u16;
typedef __attribute__((ext_vector_type(8))) short short8;
typedef __attribute__((ext_vector_type(4))) float f32x4;

#define LDSPAD 264       // 256 + 8 pad for proj weight tile

// dst-bucketing: 128 nodes per bucket (dst>>7); one p4 block per bucket
#define BP 1563          // ceil(200000/128) photo buckets
#define BU 782           // ceil(100000/128) user buckets
#define NB (BP + BU)     // 2345
#define NE4 250000       // int4 count per etype edge array
#define TOT4 (2 * NE4)   // 500000 combined int4 index space

// f32 -> bf16 bits, round-to-nearest-even
__device__ inline u16 f2b(float f) {
    union { float f; unsigned u; } v; v.f = f;
    unsigned r = v.u + 0x7FFF + ((v.u >> 16) & 1);
    return (u16)(r >> 16);
}
__device__ inline float b2f(u16 h) {
    union { unsigned u; float f; } v; v.u = ((unsigned)h) << 16; return v.f;
}

// ---- dispatch 1: transpose both W -> bf16 Wt; zero bucket_cnt ----
__global__ __launch_bounds__(256) void prep0(const float* __restrict__ W_likes,
                                             const float* __restrict__ W_likedby,
                                             u16* __restrict__ Wt_likes,
                                             u16* __restrict__ Wt_likedby,
                                             int* __restrict__ bucket_cnt) {
    int i = blockIdx.x * 256 + threadIdx.x;   // 16384 threads
    if (i < INF * OUTF) {
        int n = i & (OUTF - 1), k = i >> 6;
        Wt_likes[n * INF + k]   = f2b(W_likes[i]);
        Wt_likedby[n * INF + k] = f2b(W_likedby[i]);
    }
    if (i < NB) bucket_cnt[i] = 0;
}

// ---- dispatch 2: Wh = feats @ W + b for BOTH etypes; bf16 MFMA (verified) ----
__global__ __launch_bounds__(256) void proj_both(
    const float* __restrict__ user_feats, const float* __restrict__ photo_feats,
    const u16* __restrict__ Wt_likes, const u16* __restrict__ Wt_likedby,
    const float* __restrict__ b_likes, const float* __restrict__ b_likedby,
    u16* __restrict__ Wh_likes, u16* __restrict__ Wh_likedby)
{
    __shared__ u16 lds_wt[OUTF * LDSPAD];   // 33792 B
    const int NB_USER_PROJ = (N_USER + 63) / 64;   // 1563
    int bb = blockIdx.x;
    const float* feats; const u16* Wt; const float* bias; u16* Wh; int nrows; int blk;
    if (bb < NB_USER_PROJ) { feats = user_feats;  Wt = Wt_likes;   bias = b_likes;   Wh = Wh_likes;   nrows = N_USER;  blk = bb; }
    else                   { feats = photo_feats; Wt = Wt_likedby; bias = b_likedby; Wh = Wh_likedby; nrows = N_PHOTO; blk = bb - NB_USER_PROJ; }

    int tid = threadIdx.x;
    for (int c = tid; c < (INF * OUTF) / 8; c += 256) {
        int n = c >> 5;
        int ko = (c & 31) * 8;
        *(short8*)&lds_wt[n * LDSPAD + ko] = *(const short8*)&Wt[n * INF + ko];
    }
    __syncthreads();

    int wave = tid >> 6, lane = tid & 63;
    int l15 = lane & 15, quad = lane >> 4;
    int r0 = blk * 64 + wave * 16;
    int arow = r0 + l15;
    bool arow_ok = arow < nrows;

    f32x4 acc[4] = {{0,0,0,0},{0,0,0,0},{0,0,0,0},{0,0,0,0}};
    const float4* ap = (const float4*)(feats + (size_t)(arow_ok ? arow : 0) * INF);

    #pragma unroll
    for (int ks = 0; ks < 8; ++ks) {
        float4 x = ap[ks * 8 + quad * 2 + 0];
        float4 y = ap[ks * 8 + quad * 2 + 1];
        short8 a = { (short)f2b(x.x), (short)f2b(x.y), (short)f2b(x.z), (short)f2b(x.w),
                     (short)f2b(y.x), (short)f2b(y.y), (short)f2b(y.z), (short)f2b(y.w) };
        #pragma unroll
        for (int nt2 = 0; nt2 < 4; ++nt2) {
            short8 b = *(const short8*)&lds_wt[(nt2 * 16 + l15) * LDSPAD + ks * 32 + quad * 8];
            acc[nt2] = __builtin_amdgcn_mfma_f32_16x16x32_bf16(a, b, acc[nt2], 0, 0, 0);
        }
    }

    #pragma unroll
    for (int nt2 = 0; nt2 < 4; ++nt2) {
        int col = nt2 * 16 + l15;
        float bv = bias[col];
        #pragma unroll
        for (int r = 0; r < 4; ++r) {
            int row = r0 + quad * 4 + r;
            if (row < nrows) {
                Wh[(size_t)row * OUTF + col] = f2b(acc[nt2][r] + bv);
            }
        }
    }
}

// ---- dispatch 3: bucket histogram (LDS-privatized; ~300k aggregated atomics) ----
__global__ __launch_bounds__(256) void p1_hist(const int* __restrict__ likes_dst,
                                               const int* __restrict__ likedby_dst,
                                               int* __restrict__ bucket_cnt) {
    __shared__ int h[NB];
    int tid = threadIdx.x;
    for (int i = tid; i < NB; i += 256) h[i] = 0;
    __syncthreads();
    int gt = blockIdx.x * 256 + tid, nt = gridDim.x * 256;
    for (int i = gt; i < TOT4; i += nt) {
        bool L = i < NE4;
        int j = L ? i : i - NE4;
        int4 d = L ? ((const int4*)likes_dst)[j] : ((const int4*)likedby_dst)[j];
        int ofs = L ? 0 : BP;
        atomicAdd(&h[ofs + (d.x >> 7)], 1);
        atomicAdd(&h[ofs + (d.y >> 7)], 1);
        atomicAdd(&h[ofs + (d.z >> 7)], 1);
        atomicAdd(&h[ofs + (d.w >> 7)], 1);
    }
    __syncthreads();
    for (int i = tid; i < NB; i += 256) {
        int c = h[i];
        if (c) atomicAdd(&bucket_cnt[i], c);
    }
}

// ---- dispatch 4: one-block exclusive scan of bucket counts -> off, cur ----
__global__ __launch_bounds__(256) void p2_scan(const int* __restrict__ bucket_cnt,
                                               int* __restrict__ bucket_off,
                                               int* __restrict__ bucket_cur) {
    __shared__ int lds[256];
    int t = threadIdx.x;
    int base_i = t * 10;                 // 2560 slots cover NB=2345
    int loc[10];
    int s = 0;
    #pragma unroll
    for (int k = 0; k < 10; ++k) {
        int idx = base_i + k;
        int v = (idx < NB) ? bucket_cnt[idx] : 0;
        loc[k] = s; s += v;
    }
    lds[t] = s;
    __syncthreads();
    for (int ofs = 1; ofs < 256; ofs <<= 1) {
        int v = (t >= ofs) ? lds[t - ofs] : 0;
        __syncthreads();
        lds[t] += v;
        __syncthreads();
    }
    int excl = lds[t] - s;
    #pragma unroll
    for (int k = 0; k < 10; ++k) {
        int idx = base_i + k;
        if (idx < NB) {
            int o = excl + loc[k];
            bucket_off[idx] = o;
            bucket_cur[idx] = o;
        }
    }
    if (t == 255) bucket_off[NB] = lds[255];
}

// ---- dispatch 5: partition edges into buckets; pack (src<<7 | dst&127) ----
// One returning atomic per (block,bucket) claims a contiguous run; per-edge
// positions come from fast LDS atomics, so global stores cluster in runs.
__global__ __launch_bounds__(256) void p3_part(
    const int* __restrict__ likes_src, const int* __restrict__ likes_dst,
    const int* __restrict__ likedby_src, const int* __restrict__ likedby_dst,
    int* __restrict__ bucket_cur, unsigned* __restrict__ part) {
    __shared__ int h[NB];
    int tid = threadIdx.x;
    for (int i = tid; i < NB; i += 256) h[i] = 0;
    __syncthreads();
    int gt = blockIdx.x * 256 + tid, nt = gridDim.x * 256;
    // sweep 1: count this block's slice
    for (int i = gt; i < TOT4; i += nt) {
        bool L = i < NE4;
        int j = L ? i : i - NE4;
        int4 d = L ? ((const int4*)likes_dst)[j] : ((const int4*)likedby_dst)[j];
        int ofs = L ? 0 : BP;
        atomicAdd(&h[ofs + (d.x >> 7)], 1);
        atomicAdd(&h[ofs + (d.y >> 7)], 1);
        atomicAdd(&h[ofs + (d.z >> 7)], 1);
        atomicAdd(&h[ofs + (d.w >> 7)], 1);
    }
    __syncthreads();
    // claim runs (h[] becomes the block's run cursor per bucket)
    for (int i = tid; i < NB; i += 256) {
        int c = h[i];
        h[i] = c ? atomicAdd(&bucket_cur[i], c) : 0;
    }
    __syncthreads();
    // sweep 2: place (order within a dst group is irrelevant: mean is
    // permutation-invariant)
    for (int i = gt; i < TOT4; i += nt) {
        bool L = i < NE4;
        int j = L ? i : i - NE4;
        int4 d = L ? ((const int4*)likes_dst)[j] : ((const int4*)likedby_dst)[j];
        int4 s = L ? ((const int4*)likes_src)[j] : ((const int4*)likedby_src)[j];
        int ofs = L ? 0 : BP;
        int p;
        p = atomicAdd(&h[ofs + (d.x >> 7)], 1); part[p] = ((unsigned)s.x << 7) | (unsigned)(d.x & 127);
        p = atomicAdd(&h[ofs + (d.y >> 7)], 1); part[p] = ((unsigned)s.y << 7) | (unsigned)(d.y & 127);
        p = atomicAdd(&h[ofs + (d.z >> 7)], 1); part[p] = ((unsigned)s.z << 7) | (unsigned)(d.z & 127);
        p = atomicAdd(&h[ofs + (d.w >> 7)], 1); part[p] = ((unsigned)s.w << 7) | (unsigned)(d.w & 127);
    }
}

// ---- dispatch 6: per-bucket reduce. One block per bucket; 128 output rows
// accumulated in LDS f32 via ds_add_f32 (no global atomics); degree in LDS;
// normalized coalesced write. Half-wave (32 lanes x 4B) per edge = 128B row load.
__global__ __launch_bounds__(256) void p4_reduce(
    const u16* __restrict__ Wh_likes, const u16* __restrict__ Wh_likedby,
    const int* __restrict__ bucket_off, const unsigned* __restrict__ part,
    float* __restrict__ out)
{
    __shared__ float acc[128 * OUTF];   // 32 KB
    __shared__ int degl[128];
    int b = blockIdx.x, t = threadIdx.x;
    const u16* Wh; float* obase; int node0, nn;
    if (b < BP) {
        Wh = Wh_likes; node0 = b << 7;
        nn = (node0 + 128 <= N_PHOTO) ? 128 : (N_PHOTO - node0);
        obase = out + ((size_t)N_USER + node0) * OUTF;
    } else {
        Wh = Wh_likedby; node0 = (b - BP) << 7;
        nn = (node0 + 128 <= N_USER) ? 128 : (N_USER - node0);
        obase = out + (size_t)node0 * OUTF;
    }
    for (int i = t; i < 128 * OUTF; i += 256) acc[i] = 0.f;
    if (t < 128) degl[t] = 0;
    __syncthreads();

    int e0 = bucket_off[b], e1 = bucket_off[b + 1];
    int hw = t >> 5, l = t & 31;    // 8 half-waves per block
    #pragma unroll 2
    for (int e = e0 + hw; e < e1; e += 8) {
        unsigned v = part[e];                     // uniform per half-wave
        int src = (int)(v >> 7), dl = (int)(v & 127);
        unsigned w = ((const unsigned*)(Wh + (size_t)src * OUTF))[l];  // 2 bf16
        float f0 = b2f((u16)(w & 0xffff));
        float f1 = b2f((u16)(w >> 16));
        atomicAdd(&acc[dl * OUTF + 2 * l], f0);
        atomicAdd(&acc[dl * OUTF + 2 * l + 1], f1);
        if (l == 0) atomicAdd(&degl[dl], 1);
    }
    __syncthreads();

    // normalize + write: nn*16 float4s, contiguous
    for (int i = t; i < nn * (OUTF / 4); i += 256) {
        int node = i >> 4;
        int dg = degl[node];
        float inv = 1.0f / (float)(dg > 1 ? dg : 1);
        float4 vv = *(const float4*)&acc[node * OUTF + (i & 15) * 4];
        vv.x *= inv; vv.y *= inv; vv.z *= inv; vv.w *= inv;
        ((float4*)obase)[i] = vv;
    }
}

extern "C" void kernel_launch(void* const* d_in, const int* in_sizes, int n_in,
                              void* d_out, int out_size, void* d_ws, size_t ws_size,
                              hipStream_t stream) {
    const float* user_feats  = (const float*)d_in[0];
    const float* photo_feats = (const float*)d_in[1];
    const float* W_likes     = (const float*)d_in[2];
    const float* b_likes     = (const float*)d_in[3];
    const float* W_likedby   = (const float*)d_in[4];
    const float* b_likedby   = (const float*)d_in[5];
    const int* likes_src     = (const int*)d_in[6];
    const int* likes_dst     = (const int*)d_in[7];
    const int* likedby_src   = (const int*)d_in[8];
    const int* likedby_dst   = (const int*)d_in[9];

    char* ws = (char*)d_ws;
    // all offsets 16B-aligned; total ~46.5 MB
    u16* Wh_likes     = (u16*)(ws + 0);          // 12,800,000
    u16* Wh_likedby   = (u16*)(ws + 12800000);   // 25,600,000
    u16* Wt_likes     = (u16*)(ws + 38400000);   // 32,768
    u16* Wt_likedby   = (u16*)(ws + 38432768);   // 32,768
    int* bucket_cnt   = (int*)(ws + 38465536);   // 9,380 -> pad 9,392
    int* bucket_off   = (int*)(ws + 38474928);   // 9,384 -> pad 9,392
    int* bucket_cur   = (int*)(ws + 38484320);   // 9,380 -> pad 9,392
    unsigned* part    = (unsigned*)(ws + 38493712); // 8,000,000 -> end 46,493,712

    float* out = (float*)d_out;

    prep0<<<64, 256, 0, stream>>>(W_likes, W_likedby, Wt_likes, Wt_likedby, bucket_cnt);

    proj_both<<<(N_USER + 63) / 64 + (N_PHOTO + 63) / 64, 256, 0, stream>>>(
        user_feats, photo_feats, Wt_likes, Wt_likedby, b_likes, b_likedby,
        Wh_likes, Wh_likedby);

    p1_hist<<<128, 256, 0, stream>>>(likes_dst, likedby_dst, bucket_cnt);

    p2_scan<<<1, 256, 0, stream>>>(bucket_cnt, bucket_off, bucket_cur);

    p3_part<<<128, 256, 0, stream>>>(likes_src, likes_dst, likedby_src, likedby_dst,
                                     bucket_cur, part);

    p4_reduce<<<NB, 256, 0, stream>>>(Wh_likes, Wh_likedby, bucket_off, part, out);
}